// Round 2
// baseline (5178.424 us; speedup 1.0000x reference)
//
#include <hip/hip_runtime.h>
#include <cstdint>
#include <cstddef>

#define Mdim 1024
#define Ndim 4096
#define Bdim 16
#define SMax 512
#define K2v  64
#define KKv  32
#define NIT  8
#define PQ   8     // proxy row chunks

// ---------------------------------------------------------------- init
__global__ __launch_bounds__(256) void k_init(const float* __restrict__ Y, float* __restrict__ Rres,
        int* __restrict__ Flags, int* __restrict__ Sold, int* __restrict__ Snew, int* __restrict__ Done){
  int idx = blockIdx.x * 256 + threadIdx.x;
  int total = Bdim * Ndim;
  for (int t = idx; t < total; t += gridDim.x * 256){
    Flags[t] = 0;
    if (t < Bdim * Mdim) Rres[t] = Y[t];
    if (t < Bdim){ Sold[t] = 0; Snew[t] = 0; Done[t] = 0; }
  }
}

// ---------------------------------------------------------------- transpose A[M][N] -> At[N][M]
__global__ __launch_bounds__(256) void k_transpose(const float* __restrict__ A, float* __restrict__ At){
  __shared__ float tile[32][33];
  int j0 = blockIdx.x * 32, i0 = blockIdx.y * 32;
  int tx = threadIdx.x, ty = threadIdx.y;   // 32 x 8
  for (int r = 0; r < 32; r += 8)
    tile[ty + r][tx] = A[(size_t)(i0 + ty + r) * Ndim + (j0 + tx)];
  __syncthreads();
  for (int r = 0; r < 32; r += 8)
    At[(size_t)(j0 + ty + r) * Mdim + (i0 + tx)] = tile[tx][ty + r];
}

// ---------------------------------------------------------------- proxy partials: PP[rq][b][j] = sum_{i in chunk} A[i][j]*r[b][i]
__global__ __launch_bounds__(256) void k_proxy(const float* __restrict__ A, const float* __restrict__ Rres,
        float* __restrict__ PP){
  int j = blockIdx.x * 256 + threadIdx.x;
  int rq = blockIdx.y;                       // 8 chunks of 128 rows
  __shared__ float Rq[Bdim][128];
  for (int e = threadIdx.x; e < Bdim * 128; e += 256){
    int b = e >> 7, i = e & 127;
    Rq[b][i] = Rres[b * Mdim + rq * 128 + i];
  }
  __syncthreads();
  float acc[Bdim];
  #pragma unroll
  for (int b = 0; b < Bdim; ++b) acc[b] = 0.0f;
  for (int i = 0; i < 128; ++i){
    float a = A[(size_t)(rq * 128 + i) * Ndim + j];
    #pragma unroll
    for (int b = 0; b < Bdim; ++b) acc[b] = fmaf(a, Rq[b][i], acc[b]);
  }
  #pragma unroll
  for (int b = 0; b < Bdim; ++b)
    PP[(size_t)(rq * Bdim + b) * Ndim + j] = acc[b];
}

// ---------------------------------------------------------------- top-64 of |proxy|, update support
__global__ __launch_bounds__(1024) void k_topk(const float* __restrict__ PP, int* __restrict__ Flags,
        int* __restrict__ Cols, int* __restrict__ Sold, int* __restrict__ Snew, const int* __restrict__ Done){
  int b = blockIdx.x;
  if (Done[b]) return;
  __shared__ unsigned long long keys[Ndim];   // 32KB
  int tid = threadIdx.x;
  for (int j = tid; j < Ndim; j += 1024){
    float v = 0.0f;
    #pragma unroll
    for (int q = 0; q < PQ; ++q) v += PP[(size_t)(q * Bdim + b) * Ndim + j];
    unsigned int ab = __float_as_uint(fabsf(v));
    keys[j] = ((unsigned long long)ab << 32) | (unsigned int)j;
  }
  __syncthreads();
  // bitonic sort, descending
  for (int ksz = 2; ksz <= Ndim; ksz <<= 1){
    for (int jsz = ksz >> 1; jsz > 0; jsz >>= 1){
      for (int t = tid; t < Ndim / 2; t += 1024){
        int i = 2 * t - (t & (jsz - 1));
        int ixj = i ^ jsz;
        unsigned long long a = keys[i], c = keys[ixj];
        bool sw = ((i & ksz) == 0) ? (a < c) : (a > c);
        if (sw){ keys[i] = c; keys[ixj] = a; }
      }
      __syncthreads();
    }
  }
  if (tid < 64){
    int s = Snew[b];
    if (tid == 0) Sold[b] = s;
    int j = (int)(keys[tid] & 0xFFFFFFFFu);
    int notin = (Flags[b * Ndim + j] == 0) ? 1 : 0;
    unsigned long long bal = __ballot(notin);
    if (notin){
      int pos = s + __popcll(bal & ((1ull << tid) - 1ull));
      Flags[b * Ndim + j] = 1;
      Cols[b * SMax + pos] = j;
    }
    if (tid == 0) Snew[b] = s + (int)__popcll(bal);
  }
}

// ---------------------------------------------------------------- incremental Gram rows + rhs entries
__global__ __launch_bounds__(256) void k_gram(const float* __restrict__ At, const float* __restrict__ Y,
        float* __restrict__ G, float* __restrict__ Bv,
        const int* __restrict__ Cols, const int* __restrict__ Sold, const int* __restrict__ Snew,
        const int* __restrict__ Done){
  int b = blockIdx.x;
  if (Done[b]) return;
  int s0 = Sold[b], s1 = Snew[b];
  int p0 = s0 + (int)blockIdx.y * 4;
  if (p0 >= s1) return;
  int np = min(4, s1 - p0);
  __shared__ float Ap[4][Mdim];   // 16KB
  int tid = threadIdx.x;
  for (int e = tid; e < 4 * Mdim; e += 256){
    int pi = e >> 10, i = e & (Mdim - 1);
    Ap[pi][i] = (p0 + pi < s1) ? At[(size_t)Cols[b * SMax + p0 + pi] * Mdim + i] : 0.0f;
  }
  __syncthreads();
  int w = tid >> 6, lane = tid & 63;
  for (int q = w; q <= s1; q += 4){    // q == s1 => rhs (dot with y)
    const float* aq = (q < s1) ? (At + (size_t)Cols[b * SMax + q] * Mdim) : (Y + (size_t)b * Mdim);
    float a0 = 0, a1 = 0, a2 = 0, a3 = 0;
    #pragma unroll
    for (int c = 0; c < 16; ++c){
      float v = aq[lane + 64 * c];
      a0 = fmaf(v, Ap[0][lane + 64 * c], a0);
      a1 = fmaf(v, Ap[1][lane + 64 * c], a1);
      a2 = fmaf(v, Ap[2][lane + 64 * c], a2);
      a3 = fmaf(v, Ap[3][lane + 64 * c], a3);
    }
    #pragma unroll
    for (int off = 32; off > 0; off >>= 1){
      a0 += __shfl_xor(a0, off);
      a1 += __shfl_xor(a1, off);
      a2 += __shfl_xor(a2, off);
      a3 += __shfl_xor(a3, off);
    }
    if (lane == 0){
      float av[4] = {a0, a1, a2, a3};
      for (int r = 0; r < np; ++r){
        int p = p0 + r;
        if (q < s1){
          G[((size_t)b * SMax + p) * SMax + q] = av[r];
          G[((size_t)b * SMax + q) * SMax + p] = av[r];
        } else {
          Bv[(size_t)b * SMax + p] = av[r];
        }
      }
    }
  }
}

// ---------------------------------------------------------------- V = Gi_old @ B,  B[k][c] = G[k][s0+c]
__global__ __launch_bounds__(256) void k_V(const float* __restrict__ G, const float* __restrict__ Gi,
        float* __restrict__ V, const int* __restrict__ Sold, const int* __restrict__ Snew,
        const int* __restrict__ Done){
  int b = blockIdx.x;
  if (Done[b]) return;
  int s0 = Sold[b], s1 = Snew[b], nn = s1 - s0;
  int i0 = (int)blockIdx.y * 64;
  if (i0 >= s0) return;
  __shared__ float Gt[64][65];
  __shared__ float Bt[64][65];
  int tid = threadIdx.x;
  int tx = tid & 15, ty = tid >> 4;
  float acc[4][4];
  #pragma unroll
  for (int r = 0; r < 4; ++r)
    #pragma unroll
    for (int c = 0; c < 4; ++c) acc[r][c] = 0.0f;
  for (int k0 = 0; k0 < s0; k0 += 64){
    for (int e = tid; e < 64 * 64; e += 256){
      int r = e >> 6, c = e & 63;
      Gt[r][c] = Gi[((size_t)b * SMax + i0 + r) * SMax + k0 + c];
      Bt[r][c] = (k0 + r < s0 && c < nn) ? G[((size_t)b * SMax + k0 + r) * SMax + s0 + c] : 0.0f;
    }
    __syncthreads();
    for (int d = 0; d < 64; ++d){
      float gv[4], bv[4];
      #pragma unroll
      for (int r = 0; r < 4; ++r) gv[r] = Gt[ty * 4 + r][d];
      #pragma unroll
      for (int c = 0; c < 4; ++c) bv[c] = Bt[d][tx * 4 + c];
      #pragma unroll
      for (int r = 0; r < 4; ++r)
        #pragma unroll
        for (int c = 0; c < 4; ++c) acc[r][c] = fmaf(gv[r], bv[c], acc[r][c]);
    }
    __syncthreads();
  }
  for (int r = 0; r < 4; ++r)
    for (int c = 0; c < 4; ++c){
      int i = i0 + ty * 4 + r, cc = tx * 4 + c;
      if (i < s0 && cc < nn)
        V[((size_t)b * SMax + i) * K2v + cc] = acc[r][c];
    }
}

// ---------------------------------------------------------------- S = Gnn - B^T V (tiled), Si = S^{-1} (in-register GJ, wave 0)
__global__ __launch_bounds__(256, 1) void k_schur(const float* __restrict__ G, const float* __restrict__ V,
        float* __restrict__ Si, const int* __restrict__ Sold, const int* __restrict__ Snew,
        const int* __restrict__ Done){
  int b = blockIdx.x;
  if (Done[b]) return;
  int s0 = Sold[b], s1 = Snew[b], nn = s1 - s0;
  __shared__ float Sm[64][65];
  __shared__ float Bt[64][65];
  __shared__ float Vt[64][65];
  int tid = threadIdx.x;
  int tx = tid & 15, ty = tid >> 4;
  float acc[4][4];
  #pragma unroll
  for (int r = 0; r < 4; ++r)
    #pragma unroll
    for (int c = 0; c < 4; ++c) acc[r][c] = 0.0f;
  // ---- S accumulation: acc[r][c] = sum_k B[k][r0+r] * V[k][c0+c], LDS-tiled
  for (int k0 = 0; k0 < s0; k0 += 64){
    for (int e = tid; e < 64 * 64; e += 256){
      int r = e >> 6, c = e & 63;
      bool ok = (k0 + r < s0) && (c < nn);
      Bt[r][c] = ok ? G[((size_t)b * SMax + k0 + r) * SMax + s0 + c] : 0.0f;
      Vt[r][c] = ok ? V[((size_t)b * SMax + k0 + r) * K2v + c] : 0.0f;
    }
    __syncthreads();
    for (int d = 0; d < 64; ++d){
      float bm[4], vv[4];
      #pragma unroll
      for (int r = 0; r < 4; ++r) bm[r] = Bt[d][ty * 4 + r];
      #pragma unroll
      for (int c = 0; c < 4; ++c) vv[c] = Vt[d][tx * 4 + c];
      #pragma unroll
      for (int r = 0; r < 4; ++r)
        #pragma unroll
        for (int c = 0; c < 4; ++c) acc[r][c] = fmaf(bm[r], vv[c], acc[r][c]);
    }
    __syncthreads();
  }
  // ---- write S (identity-padded) into LDS
  for (int r = 0; r < 4; ++r)
    for (int c = 0; c < 4; ++c){
      int rr = ty * 4 + r, cc = tx * 4 + c;
      float sval;
      if (rr < nn && cc < nn)
        sval = G[((size_t)b * SMax + s0 + rr) * SMax + s0 + cc] - acc[r][c];
      else
        sval = (rr == cc) ? 1.0f : 0.0f;
      Sm[rr][cc] = sval;
    }
  __syncthreads();
  // ---- in-register Gauss-Jordan on wave 0: lane = column
  if (tid < 64){
    float s[64], w[64];
    #pragma unroll
    for (int r = 0; r < 64; ++r){
      s[r] = Sm[r][tid];
      w[r] = (r == tid) ? 1.0f : 0.0f;
    }
    #pragma unroll
    for (int j = 0; j < 64; ++j){
      float piv = __uint_as_float((unsigned)__builtin_amdgcn_readlane((int)__float_as_uint(s[j]), j));
      float rp = 1.0f / piv;
      s[j] *= rp;
      w[j] *= rp;
      #pragma unroll
      for (int i = 0; i < 64; ++i){
        if (i == j) continue;
        float f = __uint_as_float((unsigned)__builtin_amdgcn_readlane((int)__float_as_uint(s[i]), j));
        s[i] = fmaf(-f, s[j], s[i]);
        w[i] = fmaf(-f, w[j], w[i]);
      }
    }
    #pragma unroll
    for (int r = 0; r < 64; ++r)
      Si[(size_t)b * K2v * K2v + r * K2v + tid] = w[r];
  }
}

// ---------------------------------------------------------------- T = V @ Si
__global__ __launch_bounds__(256) void k_T(const float* __restrict__ V, const float* __restrict__ Si,
        float* __restrict__ T, const int* __restrict__ Sold, const int* __restrict__ Snew,
        const int* __restrict__ Done){
  int b = blockIdx.x;
  if (Done[b]) return;
  int s0 = Sold[b], s1 = Snew[b], nn = s1 - s0;
  int i0 = (int)blockIdx.y * 64;
  if (i0 >= s0) return;
  __shared__ float Vt[64][65];
  __shared__ float Ss[64][65];
  int tid = threadIdx.x;
  for (int e = tid; e < 64 * 64; e += 256){
    int r = e >> 6, c = e & 63;
    Vt[r][c] = (i0 + r < s0 && c < nn) ? V[((size_t)b * SMax + i0 + r) * K2v + c] : 0.0f;
    Ss[r][c] = Si[(size_t)b * K2v * K2v + e];
  }
  __syncthreads();
  int tx = tid & 15, ty = tid >> 4;
  float acc[4][4];
  #pragma unroll
  for (int r = 0; r < 4; ++r)
    #pragma unroll
    for (int c = 0; c < 4; ++c) acc[r][c] = 0.0f;
  for (int d = 0; d < 64; ++d){
    float vv[4], sv[4];
    #pragma unroll
    for (int r = 0; r < 4; ++r) vv[r] = Vt[ty * 4 + r][d];
    #pragma unroll
    for (int c = 0; c < 4; ++c) sv[c] = Ss[d][tx * 4 + c];
    #pragma unroll
    for (int r = 0; r < 4; ++r)
      #pragma unroll
      for (int c = 0; c < 4; ++c) acc[r][c] = fmaf(vv[r], sv[c], acc[r][c]);
  }
  for (int r = 0; r < 4; ++r)
    for (int c = 0; c < 4; ++c){
      int i = i0 + ty * 4 + r, dd = tx * 4 + c;
      if (i < s0 && dd < nn)
        T[((size_t)b * SMax + i) * K2v + dd] = acc[r][c];
    }
}

// ---------------------------------------------------------------- Gi <- bordered inverse update (in place)
__global__ __launch_bounds__(256) void k_upd(float* __restrict__ Gi, const float* __restrict__ T,
        const float* __restrict__ V, const float* __restrict__ Si,
        const int* __restrict__ Sold, const int* __restrict__ Snew, const int* __restrict__ Done){
  int b = blockIdx.x;
  if (Done[b]) return;
  int s0 = Sold[b], s1 = Snew[b];
  int i0 = (int)blockIdx.y * 64, k0 = (int)blockIdx.z * 64;
  if (i0 >= s1 || k0 >= s1) return;
  int nn = s1 - s0;
  __shared__ float Tt[64][65];
  __shared__ float Vk[64][65];
  __shared__ float Tk[64][65];
  int tid = threadIdx.x;
  for (int e = tid; e < 64 * 64; e += 256){
    int r = e >> 6, c = e & 63;
    Tt[r][c] = (i0 + r < s0 && c < nn) ? T[((size_t)b * SMax + i0 + r) * K2v + c] : 0.0f;
    Tk[r][c] = (k0 + r < s0 && c < nn) ? T[((size_t)b * SMax + k0 + r) * K2v + c] : 0.0f;
    Vk[r][c] = (k0 + r < s0 && c < nn) ? V[((size_t)b * SMax + k0 + r) * K2v + c] : 0.0f;
  }
  __syncthreads();
  int tx = tid & 15, ty = tid >> 4;
  float acc[4][4];
  #pragma unroll
  for (int r = 0; r < 4; ++r)
    #pragma unroll
    for (int c = 0; c < 4; ++c) acc[r][c] = 0.0f;
  for (int d = 0; d < 64; ++d){
    float tv[4], vv[4];
    #pragma unroll
    for (int r = 0; r < 4; ++r) tv[r] = Tt[ty * 4 + r][d];
    #pragma unroll
    for (int c = 0; c < 4; ++c) vv[c] = Vk[tx * 4 + c][d];
    #pragma unroll
    for (int r = 0; r < 4; ++r)
      #pragma unroll
      for (int c = 0; c < 4; ++c) acc[r][c] = fmaf(tv[r], vv[c], acc[r][c]);
  }
  for (int r = 0; r < 4; ++r)
    for (int c = 0; c < 4; ++c){
      int i = i0 + ty * 4 + r, k = k0 + tx * 4 + c;
      if (i < s1 && k < s1){
        size_t idx = ((size_t)b * SMax + i) * SMax + k;
        float val;
        if (i < s0){
          if (k < s0) val = Gi[idx] + acc[r][c];
          else        val = -Tt[ty * 4 + r][k - s0];
        } else {
          if (k < s0) val = -Tk[tx * 4 + c][i - s0];
          else        val = Si[(size_t)b * K2v * K2v + (i - s0) * K2v + (k - s0)];
        }
        Gi[idx] = val;
      }
    }
}

// ---------------------------------------------------------------- fused solve (z0 -> refine -> zz) + top-32 + residual
__global__ __launch_bounds__(512) void k_solve(const float* __restrict__ G, const float* __restrict__ Gi,
        const float* __restrict__ Bv, const float* __restrict__ At, const float* __restrict__ Y,
        const int* __restrict__ Cols, const int* __restrict__ Snew, int* __restrict__ Done,
        float* __restrict__ XKval, int* __restrict__ XKcol, float* __restrict__ Rres){
  int b = blockIdx.x;
  if (Done[b]) return;
  int s1 = Snew[b];
  __shared__ float vs[SMax];     // Bv
  __shared__ float z0[SMax];     // z0 then final z
  __shared__ float r2[SMax];
  __shared__ unsigned long long sk[SMax];
  __shared__ float xv[KKv];
  __shared__ int   xc[KKv];
  __shared__ float red[8];
  int tid = threadIdx.x;
  int w = tid >> 6, lane = tid & 63;
  vs[tid] = (tid < s1) ? Bv[(size_t)b * SMax + tid] : 0.0f;
  z0[tid] = 0.0f;
  r2[tid] = 0.0f;
  __syncthreads();
  // pass 1: z0 = Gi @ Bv
  for (int i = w; i < s1; i += 8){
    const float* row = Gi + ((size_t)b * SMax + i) * SMax;
    float a = 0;
    #pragma unroll
    for (int c = 0; c < 8; ++c) a = fmaf(row[lane + 64 * c], vs[lane + 64 * c], a);
    #pragma unroll
    for (int off = 32; off > 0; off >>= 1) a += __shfl_xor(a, off);
    if (lane == 0) z0[i] = a;
  }
  __syncthreads();
  // pass 2: r2 = Bv - G @ z0
  for (int i = w; i < s1; i += 8){
    const float* row = G + ((size_t)b * SMax + i) * SMax;
    float a = 0;
    #pragma unroll
    for (int c = 0; c < 8; ++c) a = fmaf(row[lane + 64 * c], z0[lane + 64 * c], a);
    #pragma unroll
    for (int off = 32; off > 0; off >>= 1) a += __shfl_xor(a, off);
    if (lane == 0) r2[i] = vs[i] - a;
  }
  __syncthreads();
  // pass 3: z = z0 + Gi @ r2
  for (int i = w; i < s1; i += 8){
    const float* row = Gi + ((size_t)b * SMax + i) * SMax;
    float a = 0;
    #pragma unroll
    for (int c = 0; c < 8; ++c) a = fmaf(row[lane + 64 * c], r2[lane + 64 * c], a);
    #pragma unroll
    for (int off = 32; off > 0; off >>= 1) a += __shfl_xor(a, off);
    if (lane == 0) z0[i] = z0[i] + a;
  }
  __syncthreads();
  // top-32 threshold: bitonic sort of SMax keys
  {
    unsigned long long key = 0;
    if (tid < s1){
      float z = z0[tid];
      unsigned int ab = __float_as_uint(fabsf(z));
      int col = Cols[b * SMax + tid];
      key = ((unsigned long long)ab << 32) | ((unsigned long long)(4095 - col) << 20) | (unsigned int)tid;
    }
    sk[tid] = key;
  }
  __syncthreads();
  for (int ksz = 2; ksz <= SMax; ksz <<= 1){
    for (int jsz = ksz >> 1; jsz > 0; jsz >>= 1){
      for (int t = tid; t < SMax / 2; t += 512){
        int i = 2 * t - (t & (jsz - 1));
        int ixj = i ^ jsz;
        unsigned long long a = sk[i], c = sk[ixj];
        bool sw = ((i & ksz) == 0) ? (a < c) : (a > c);
        if (sw){ sk[i] = c; sk[ixj] = a; }
      }
      __syncthreads();
    }
  }
  if (tid < KKv){
    unsigned long long key = sk[tid];
    int p = (int)(key & 0xFFFFFu);
    float v = z0[p];
    xv[tid] = v;
    xc[tid] = Cols[b * SMax + p];
    XKval[b * KKv + tid] = v;
    XKcol[b * KKv + tid] = xc[tid];
  }
  __syncthreads();
  // residual r = y - sum_t xv[t]*At[xc[t]]  (2 rows per thread)
  int i1 = tid, i2 = tid + 512;
  float ra = Y[(size_t)b * Mdim + i1];
  float rb = Y[(size_t)b * Mdim + i2];
  for (int t = 0; t < KKv; ++t){
    const float* colp = At + (size_t)xc[t] * Mdim;
    float v = xv[t];
    ra = fmaf(-v, colp[i1], ra);
    rb = fmaf(-v, colp[i2], rb);
  }
  Rres[(size_t)b * Mdim + i1] = ra;
  Rres[(size_t)b * Mdim + i2] = rb;
  float ss = ra * ra + rb * rb;
  #pragma unroll
  for (int off = 32; off > 0; off >>= 1) ss += __shfl_xor(ss, off);
  if (lane == 0) red[w] = ss;
  __syncthreads();
  if (tid == 0){
    float tot = 0;
    for (int q = 0; q < 8; ++q) tot += red[q];
    if (tot < 1e-12f) Done[b] = 1;
  }
}

// ---------------------------------------------------------------- dense output
__global__ __launch_bounds__(1024) void k_output(const float* __restrict__ XKval, const int* __restrict__ XKcol,
        float* __restrict__ out){
  int b = blockIdx.x;
  __shared__ float xv[KKv];
  __shared__ int   xc[KKv];
  if (threadIdx.x < KKv){
    xv[threadIdx.x] = XKval[b * KKv + threadIdx.x];
    xc[threadIdx.x] = XKcol[b * KKv + threadIdx.x];
  }
  __syncthreads();
  int j = blockIdx.y * 1024 + threadIdx.x;
  float v = 0.0f;
  #pragma unroll
  for (int t = 0; t < KKv; ++t) v = (xc[t] == j) ? xv[t] : v;
  out[(size_t)b * Ndim + j] = v;
}

// ----------------------------------------------------------------
extern "C" void kernel_launch(void* const* d_in, const int* in_sizes, int n_in,
                              void* d_out, int out_size, void* d_ws, size_t ws_size,
                              hipStream_t stream){
  const float* Y = (const float*)d_in[0];   // [B][M]
  const float* A = (const float*)d_in[1];   // [M][N]
  float* ws = (float*)d_ws;
  size_t off = 0;
  float* At   = ws + off; off += (size_t)Ndim * Mdim;          // 4.19M
  float* G    = ws + off; off += (size_t)Bdim * SMax * SMax;   // 4.19M
  float* Gi   = ws + off; off += (size_t)Bdim * SMax * SMax;   // 4.19M
  float* V    = ws + off; off += (size_t)Bdim * SMax * K2v;    // 0.52M
  float* T    = ws + off; off += (size_t)Bdim * SMax * K2v;    // 0.52M
  float* Si   = ws + off; off += (size_t)Bdim * K2v * K2v;
  float* PP   = ws + off; off += (size_t)PQ * Bdim * Ndim;
  float* Rres = ws + off; off += (size_t)Bdim * Mdim;
  float* Bv   = ws + off; off += (size_t)Bdim * SMax;
  float* XKval = ws + off; off += (size_t)Bdim * KKv;
  int* XKcol = (int*)(ws + off); off += (size_t)Bdim * KKv;
  int* Cols  = (int*)(ws + off); off += (size_t)Bdim * SMax;
  int* Flags = (int*)(ws + off); off += (size_t)Bdim * Ndim;
  int* Sold  = (int*)(ws + off); off += Bdim;
  int* Snew  = (int*)(ws + off); off += Bdim;
  int* Done  = (int*)(ws + off); off += Bdim;

  k_init<<<256, 256, 0, stream>>>(Y, Rres, Flags, Sold, Snew, Done);
  k_transpose<<<dim3(Ndim / 32, Mdim / 32), dim3(32, 8), 0, stream>>>(A, At);
  for (int t = 0; t < NIT; ++t){
    k_proxy<<<dim3(Ndim / 256, PQ), 256, 0, stream>>>(A, Rres, PP);
    k_topk<<<Bdim, 1024, 0, stream>>>(PP, Flags, Cols, Sold, Snew, Done);
    k_gram<<<dim3(Bdim, 16), 256, 0, stream>>>(At, Y, G, Bv, Cols, Sold, Snew, Done);
    if (t > 0)
      k_V<<<dim3(Bdim, t), 256, 0, stream>>>(G, Gi, V, Sold, Snew, Done);
    k_schur<<<Bdim, 256, 0, stream>>>(G, V, Si, Sold, Snew, Done);
    if (t > 0)
      k_T<<<dim3(Bdim, t), 256, 0, stream>>>(V, Si, T, Sold, Snew, Done);
    k_upd<<<dim3(Bdim, t + 1, t + 1), 256, 0, stream>>>(Gi, T, V, Si, Sold, Snew, Done);
    k_solve<<<Bdim, 512, 0, stream>>>(G, Gi, Bv, At, Y, Cols, Snew, Done, XKval, XKcol, Rres);
  }
  k_output<<<dim3(Bdim, Ndim / 1024), 1024, 0, stream>>>(XKval, XKcol, (float*)d_out);
}

// Round 3
// 2124.481 us; speedup vs baseline: 2.4375x; 2.4375x over previous
//
#include <hip/hip_runtime.h>
#include <cstdint>
#include <cstddef>

#define Mdim 1024
#define Ndim 4096
#define Bdim 16
#define SMax 512
#define K2v  64
#define KKv  32
#define NIT  8
#define PQ   8     // proxy row chunks

// ---------------------------------------------------------------- init
__global__ __launch_bounds__(256) void k_init(const float* __restrict__ Y, float* __restrict__ Rres,
        int* __restrict__ Flags, int* __restrict__ Sold, int* __restrict__ Snew, int* __restrict__ Done){
  int idx = blockIdx.x * 256 + threadIdx.x;
  int total = Bdim * Ndim;
  for (int t = idx; t < total; t += gridDim.x * 256){
    Flags[t] = 0;
    if (t < Bdim * Mdim) Rres[t] = Y[t];
    if (t < Bdim){ Sold[t] = 0; Snew[t] = 0; Done[t] = 0; }
  }
}

// ---------------------------------------------------------------- transpose A[M][N] -> At[N][M]
__global__ __launch_bounds__(256) void k_transpose(const float* __restrict__ A, float* __restrict__ At){
  __shared__ float tile[32][33];
  int j0 = blockIdx.x * 32, i0 = blockIdx.y * 32;
  int tx = threadIdx.x, ty = threadIdx.y;   // 32 x 8
  for (int r = 0; r < 32; r += 8)
    tile[ty + r][tx] = A[(size_t)(i0 + ty + r) * Ndim + (j0 + tx)];
  __syncthreads();
  for (int r = 0; r < 32; r += 8)
    At[(size_t)(j0 + ty + r) * Mdim + (i0 + tx)] = tile[tx][ty + r];
}

// ---------------------------------------------------------------- proxy partials: PP[rq][b][j] = sum_{i in chunk} A[i][j]*r[b][i]
__global__ __launch_bounds__(256) void k_proxy(const float* __restrict__ A, const float* __restrict__ Rres,
        float* __restrict__ PP){
  int j = blockIdx.x * 256 + threadIdx.x;
  int rq = blockIdx.y;                       // 8 chunks of 128 rows
  __shared__ float Rq[Bdim][128];
  for (int e = threadIdx.x; e < Bdim * 128; e += 256){
    int b = e >> 7, i = e & 127;
    Rq[b][i] = Rres[b * Mdim + rq * 128 + i];
  }
  __syncthreads();
  float acc[Bdim];
  #pragma unroll
  for (int b = 0; b < Bdim; ++b) acc[b] = 0.0f;
  for (int i = 0; i < 128; ++i){
    float a = A[(size_t)(rq * 128 + i) * Ndim + j];
    #pragma unroll
    for (int b = 0; b < Bdim; ++b) acc[b] = fmaf(a, Rq[b][i], acc[b]);
  }
  #pragma unroll
  for (int b = 0; b < Bdim; ++b)
    PP[(size_t)(rq * Bdim + b) * Ndim + j] = acc[b];
}

// ---------------------------------------------------------------- top-64 of |proxy|, update support
__global__ __launch_bounds__(1024) void k_topk(const float* __restrict__ PP, int* __restrict__ Flags,
        int* __restrict__ Cols, int* __restrict__ Sold, int* __restrict__ Snew, const int* __restrict__ Done){
  int b = blockIdx.x;
  if (Done[b]) return;
  __shared__ unsigned long long keys[Ndim];   // 32KB
  int tid = threadIdx.x;
  for (int j = tid; j < Ndim; j += 1024){
    float v = 0.0f;
    #pragma unroll
    for (int q = 0; q < PQ; ++q) v += PP[(size_t)(q * Bdim + b) * Ndim + j];
    unsigned int ab = __float_as_uint(fabsf(v));
    keys[j] = ((unsigned long long)ab << 32) | (unsigned int)j;
  }
  __syncthreads();
  // bitonic sort, descending
  for (int ksz = 2; ksz <= Ndim; ksz <<= 1){
    for (int jsz = ksz >> 1; jsz > 0; jsz >>= 1){
      for (int t = tid; t < Ndim / 2; t += 1024){
        int i = 2 * t - (t & (jsz - 1));
        int ixj = i ^ jsz;
        unsigned long long a = keys[i], c = keys[ixj];
        bool sw = ((i & ksz) == 0) ? (a < c) : (a > c);
        if (sw){ keys[i] = c; keys[ixj] = a; }
      }
      __syncthreads();
    }
  }
  if (tid < 64){
    int s = Snew[b];
    if (tid == 0) Sold[b] = s;
    int j = (int)(keys[tid] & 0xFFFFFFFFu);
    int notin = (Flags[b * Ndim + j] == 0) ? 1 : 0;
    unsigned long long bal = __ballot(notin);
    if (notin){
      int pos = s + __popcll(bal & ((1ull << tid) - 1ull));
      Flags[b * Ndim + j] = 1;
      Cols[b * SMax + pos] = j;
    }
    if (tid == 0) Snew[b] = s + (int)__popcll(bal);
  }
}

// ---------------------------------------------------------------- incremental Gram rows + rhs entries
__global__ __launch_bounds__(256) void k_gram(const float* __restrict__ At, const float* __restrict__ Y,
        float* __restrict__ G, float* __restrict__ Bv,
        const int* __restrict__ Cols, const int* __restrict__ Sold, const int* __restrict__ Snew,
        const int* __restrict__ Done){
  int b = blockIdx.x;
  if (Done[b]) return;
  int s0 = Sold[b], s1 = Snew[b];
  int p0 = s0 + (int)blockIdx.y * 4;
  if (p0 >= s1) return;
  int np = min(4, s1 - p0);
  __shared__ float Ap[4][Mdim];   // 16KB
  int tid = threadIdx.x;
  for (int e = tid; e < 4 * Mdim; e += 256){
    int pi = e >> 10, i = e & (Mdim - 1);
    Ap[pi][i] = (p0 + pi < s1) ? At[(size_t)Cols[b * SMax + p0 + pi] * Mdim + i] : 0.0f;
  }
  __syncthreads();
  int w = tid >> 6, lane = tid & 63;
  for (int q = w; q <= s1; q += 4){    // q == s1 => rhs (dot with y)
    const float* aq = (q < s1) ? (At + (size_t)Cols[b * SMax + q] * Mdim) : (Y + (size_t)b * Mdim);
    float a0 = 0, a1 = 0, a2 = 0, a3 = 0;
    #pragma unroll
    for (int c = 0; c < 16; ++c){
      float v = aq[lane + 64 * c];
      a0 = fmaf(v, Ap[0][lane + 64 * c], a0);
      a1 = fmaf(v, Ap[1][lane + 64 * c], a1);
      a2 = fmaf(v, Ap[2][lane + 64 * c], a2);
      a3 = fmaf(v, Ap[3][lane + 64 * c], a3);
    }
    #pragma unroll
    for (int off = 32; off > 0; off >>= 1){
      a0 += __shfl_xor(a0, off);
      a1 += __shfl_xor(a1, off);
      a2 += __shfl_xor(a2, off);
      a3 += __shfl_xor(a3, off);
    }
    if (lane == 0){
      float av[4] = {a0, a1, a2, a3};
      for (int r = 0; r < np; ++r){
        int p = p0 + r;
        if (q < s1){
          G[((size_t)b * SMax + p) * SMax + q] = av[r];
          G[((size_t)b * SMax + q) * SMax + p] = av[r];
        } else {
          Bv[(size_t)b * SMax + p] = av[r];
        }
      }
    }
  }
}

// ---------------------------------------------------------------- V = Gi_old @ B,  B[k][c] = G[k][s0+c]
__global__ __launch_bounds__(256) void k_V(const float* __restrict__ G, const float* __restrict__ Gi,
        float* __restrict__ V, const int* __restrict__ Sold, const int* __restrict__ Snew,
        const int* __restrict__ Done){
  int b = blockIdx.x;
  if (Done[b]) return;
  int s0 = Sold[b], s1 = Snew[b], nn = s1 - s0;
  int i0 = (int)blockIdx.y * 64;
  if (i0 >= s0) return;
  __shared__ float Gt[64][65];
  __shared__ float Bt[64][65];
  int tid = threadIdx.x;
  int tx = tid & 15, ty = tid >> 4;
  float acc[4][4];
  #pragma unroll
  for (int r = 0; r < 4; ++r)
    #pragma unroll
    for (int c = 0; c < 4; ++c) acc[r][c] = 0.0f;
  for (int k0 = 0; k0 < s0; k0 += 64){
    for (int e = tid; e < 64 * 64; e += 256){
      int r = e >> 6, c = e & 63;
      Gt[r][c] = Gi[((size_t)b * SMax + i0 + r) * SMax + k0 + c];
      Bt[r][c] = (k0 + r < s0 && c < nn) ? G[((size_t)b * SMax + k0 + r) * SMax + s0 + c] : 0.0f;
    }
    __syncthreads();
    for (int d = 0; d < 64; ++d){
      float gv[4], bv[4];
      #pragma unroll
      for (int r = 0; r < 4; ++r) gv[r] = Gt[ty * 4 + r][d];
      #pragma unroll
      for (int c = 0; c < 4; ++c) bv[c] = Bt[d][tx * 4 + c];
      #pragma unroll
      for (int r = 0; r < 4; ++r)
        #pragma unroll
        for (int c = 0; c < 4; ++c) acc[r][c] = fmaf(gv[r], bv[c], acc[r][c]);
    }
    __syncthreads();
  }
  for (int r = 0; r < 4; ++r)
    for (int c = 0; c < 4; ++c){
      int i = i0 + ty * 4 + r, cc = tx * 4 + c;
      if (i < s0 && cc < nn)
        V[((size_t)b * SMax + i) * K2v + cc] = acc[r][c];
    }
}

// ---------------------------------------------------------------- S = Gnn - B^T V (tiled), Si = S^{-1} (LDS Gauss-Jordan)
__global__ __launch_bounds__(256) void k_schur(const float* __restrict__ G, const float* __restrict__ V,
        float* __restrict__ Si, const int* __restrict__ Sold, const int* __restrict__ Snew,
        const int* __restrict__ Done){
  int b = blockIdx.x;
  if (Done[b]) return;
  int s0 = Sold[b], s1 = Snew[b], nn = s1 - s0;
  __shared__ float Sm[64][65];
  __shared__ float Wm[64][65];
  __shared__ float Bt[64][65];
  __shared__ float Vt[64][65];
  int tid = threadIdx.x;
  int tx = tid & 15, ty = tid >> 4;
  float acc[4][4];
  #pragma unroll
  for (int r = 0; r < 4; ++r)
    #pragma unroll
    for (int c = 0; c < 4; ++c) acc[r][c] = 0.0f;
  // ---- S accumulation: acc[r][c] = sum_k B[k][r0+r] * V[k][c0+c], LDS-tiled
  for (int k0 = 0; k0 < s0; k0 += 64){
    for (int e = tid; e < 64 * 64; e += 256){
      int r = e >> 6, c = e & 63;
      bool ok = (k0 + r < s0) && (c < nn);
      Bt[r][c] = ok ? G[((size_t)b * SMax + k0 + r) * SMax + s0 + c] : 0.0f;
      Vt[r][c] = ok ? V[((size_t)b * SMax + k0 + r) * K2v + c] : 0.0f;
    }
    __syncthreads();
    for (int d = 0; d < 64; ++d){
      float bm[4], vv[4];
      #pragma unroll
      for (int r = 0; r < 4; ++r) bm[r] = Bt[d][ty * 4 + r];
      #pragma unroll
      for (int c = 0; c < 4; ++c) vv[c] = Vt[d][tx * 4 + c];
      #pragma unroll
      for (int r = 0; r < 4; ++r)
        #pragma unroll
        for (int c = 0; c < 4; ++c) acc[r][c] = fmaf(bm[r], vv[c], acc[r][c]);
    }
    __syncthreads();
  }
  // ---- write S (identity-padded) into LDS, Wm = I
  for (int r = 0; r < 4; ++r)
    for (int c = 0; c < 4; ++c){
      int rr = ty * 4 + r, cc = tx * 4 + c;
      float sval;
      if (rr < nn && cc < nn)
        sval = G[((size_t)b * SMax + s0 + rr) * SMax + s0 + cc] - acc[r][c];
      else
        sval = (rr == cc) ? 1.0f : 0.0f;
      Sm[rr][cc] = sval;
      Wm[rr][cc] = (rr == cc) ? 1.0f : 0.0f;
    }
  __syncthreads();
  // ---- LDS Gauss-Jordan: wave 0 normalizes pivot row; all 256 threads eliminate
  for (int j = 0; j < 64; ++j){
    if (tid < 64){
      float rp = 1.0f / Sm[j][j];     // single-wave lockstep: all reads before writes
      Sm[j][tid] *= rp;
      Wm[j][tid] *= rp;
    }
    __syncthreads();
    int i = tid >> 2, cg = tid & 3;   // 4 threads per row (same wave), 16 cols each
    float f = Sm[i][j];               // in-wave lockstep: read before any write below
    if (i != j){
      #pragma unroll
      for (int cc = 0; cc < 16; ++cc){
        int c = cg + cc * 4;
        Sm[i][c] = fmaf(-f, Sm[j][c], Sm[i][c]);
        Wm[i][c] = fmaf(-f, Wm[j][c], Wm[i][c]);
      }
    }
    __syncthreads();
  }
  for (int e = tid; e < 64 * 64; e += 256)
    Si[(size_t)b * K2v * K2v + e] = Wm[e >> 6][e & 63];
}

// ---------------------------------------------------------------- T = V @ Si
__global__ __launch_bounds__(256) void k_T(const float* __restrict__ V, const float* __restrict__ Si,
        float* __restrict__ T, const int* __restrict__ Sold, const int* __restrict__ Snew,
        const int* __restrict__ Done){
  int b = blockIdx.x;
  if (Done[b]) return;
  int s0 = Sold[b], s1 = Snew[b], nn = s1 - s0;
  int i0 = (int)blockIdx.y * 64;
  if (i0 >= s0) return;
  __shared__ float Vt[64][65];
  __shared__ float Ss[64][65];
  int tid = threadIdx.x;
  for (int e = tid; e < 64 * 64; e += 256){
    int r = e >> 6, c = e & 63;
    Vt[r][c] = (i0 + r < s0 && c < nn) ? V[((size_t)b * SMax + i0 + r) * K2v + c] : 0.0f;
    Ss[r][c] = Si[(size_t)b * K2v * K2v + e];
  }
  __syncthreads();
  int tx = tid & 15, ty = tid >> 4;
  float acc[4][4];
  #pragma unroll
  for (int r = 0; r < 4; ++r)
    #pragma unroll
    for (int c = 0; c < 4; ++c) acc[r][c] = 0.0f;
  for (int d = 0; d < 64; ++d){
    float vv[4], sv[4];
    #pragma unroll
    for (int r = 0; r < 4; ++r) vv[r] = Vt[ty * 4 + r][d];
    #pragma unroll
    for (int c = 0; c < 4; ++c) sv[c] = Ss[d][tx * 4 + c];
    #pragma unroll
    for (int r = 0; r < 4; ++r)
      #pragma unroll
      for (int c = 0; c < 4; ++c) acc[r][c] = fmaf(vv[r], sv[c], acc[r][c]);
  }
  for (int r = 0; r < 4; ++r)
    for (int c = 0; c < 4; ++c){
      int i = i0 + ty * 4 + r, dd = tx * 4 + c;
      if (i < s0 && dd < nn)
        T[((size_t)b * SMax + i) * K2v + dd] = acc[r][c];
    }
}

// ---------------------------------------------------------------- Gi <- bordered inverse update (in place)
__global__ __launch_bounds__(256) void k_upd(float* __restrict__ Gi, const float* __restrict__ T,
        const float* __restrict__ V, const float* __restrict__ Si,
        const int* __restrict__ Sold, const int* __restrict__ Snew, const int* __restrict__ Done){
  int b = blockIdx.x;
  if (Done[b]) return;
  int s0 = Sold[b], s1 = Snew[b];
  int i0 = (int)blockIdx.y * 64, k0 = (int)blockIdx.z * 64;
  if (i0 >= s1 || k0 >= s1) return;
  int nn = s1 - s0;
  __shared__ float Tt[64][65];
  __shared__ float Vk[64][65];
  __shared__ float Tk[64][65];
  int tid = threadIdx.x;
  for (int e = tid; e < 64 * 64; e += 256){
    int r = e >> 6, c = e & 63;
    Tt[r][c] = (i0 + r < s0 && c < nn) ? T[((size_t)b * SMax + i0 + r) * K2v + c] : 0.0f;
    Tk[r][c] = (k0 + r < s0 && c < nn) ? T[((size_t)b * SMax + k0 + r) * K2v + c] : 0.0f;
    Vk[r][c] = (k0 + r < s0 && c < nn) ? V[((size_t)b * SMax + k0 + r) * K2v + c] : 0.0f;
  }
  __syncthreads();
  int tx = tid & 15, ty = tid >> 4;
  float acc[4][4];
  #pragma unroll
  for (int r = 0; r < 4; ++r)
    #pragma unroll
    for (int c = 0; c < 4; ++c) acc[r][c] = 0.0f;
  for (int d = 0; d < 64; ++d){
    float tv[4], vv[4];
    #pragma unroll
    for (int r = 0; r < 4; ++r) tv[r] = Tt[ty * 4 + r][d];
    #pragma unroll
    for (int c = 0; c < 4; ++c) vv[c] = Vk[tx * 4 + c][d];
    #pragma unroll
    for (int r = 0; r < 4; ++r)
      #pragma unroll
      for (int c = 0; c < 4; ++c) acc[r][c] = fmaf(tv[r], vv[c], acc[r][c]);
  }
  for (int r = 0; r < 4; ++r)
    for (int c = 0; c < 4; ++c){
      int i = i0 + ty * 4 + r, k = k0 + tx * 4 + c;
      if (i < s1 && k < s1){
        size_t idx = ((size_t)b * SMax + i) * SMax + k;
        float val;
        if (i < s0){
          if (k < s0) val = Gi[idx] + acc[r][c];
          else        val = -Tt[ty * 4 + r][k - s0];
        } else {
          if (k < s0) val = -Tk[tx * 4 + c][i - s0];
          else        val = Si[(size_t)b * K2v * K2v + (i - s0) * K2v + (k - s0)];
        }
        Gi[idx] = val;
      }
    }
}

// ---------------------------------------------------------------- fused solve (z0 -> refine -> zz) + top-32 + residual
__global__ __launch_bounds__(512) void k_solve(const float* __restrict__ G, const float* __restrict__ Gi,
        const float* __restrict__ Bv, const float* __restrict__ At, const float* __restrict__ Y,
        const int* __restrict__ Cols, const int* __restrict__ Snew, int* __restrict__ Done,
        float* __restrict__ XKval, int* __restrict__ XKcol, float* __restrict__ Rres){
  int b = blockIdx.x;
  if (Done[b]) return;
  int s1 = Snew[b];
  __shared__ float vs[SMax];     // Bv
  __shared__ float z0[SMax];     // z0 then final z
  __shared__ float r2[SMax];
  __shared__ unsigned long long sk[SMax];
  __shared__ float xv[KKv];
  __shared__ int   xc[KKv];
  __shared__ float red[8];
  int tid = threadIdx.x;
  int w = tid >> 6, lane = tid & 63;
  vs[tid] = (tid < s1) ? Bv[(size_t)b * SMax + tid] : 0.0f;
  z0[tid] = 0.0f;
  r2[tid] = 0.0f;
  __syncthreads();
  // pass 1: z0 = Gi @ Bv
  for (int i = w; i < s1; i += 8){
    const float* row = Gi + ((size_t)b * SMax + i) * SMax;
    float a = 0;
    #pragma unroll
    for (int c = 0; c < 8; ++c) a = fmaf(row[lane + 64 * c], vs[lane + 64 * c], a);
    #pragma unroll
    for (int off = 32; off > 0; off >>= 1) a += __shfl_xor(a, off);
    if (lane == 0) z0[i] = a;
  }
  __syncthreads();
  // pass 2: r2 = Bv - G @ z0
  for (int i = w; i < s1; i += 8){
    const float* row = G + ((size_t)b * SMax + i) * SMax;
    float a = 0;
    #pragma unroll
    for (int c = 0; c < 8; ++c) a = fmaf(row[lane + 64 * c], z0[lane + 64 * c], a);
    #pragma unroll
    for (int off = 32; off > 0; off >>= 1) a += __shfl_xor(a, off);
    if (lane == 0) r2[i] = vs[i] - a;
  }
  __syncthreads();
  // pass 3: z = z0 + Gi @ r2
  for (int i = w; i < s1; i += 8){
    const float* row = Gi + ((size_t)b * SMax + i) * SMax;
    float a = 0;
    #pragma unroll
    for (int c = 0; c < 8; ++c) a = fmaf(row[lane + 64 * c], r2[lane + 64 * c], a);
    #pragma unroll
    for (int off = 32; off > 0; off >>= 1) a += __shfl_xor(a, off);
    if (lane == 0) z0[i] = z0[i] + a;
  }
  __syncthreads();
  // top-32 threshold: bitonic sort of SMax keys
  {
    unsigned long long key = 0;
    if (tid < s1){
      float z = z0[tid];
      unsigned int ab = __float_as_uint(fabsf(z));
      int col = Cols[b * SMax + tid];
      key = ((unsigned long long)ab << 32) | ((unsigned long long)(4095 - col) << 20) | (unsigned int)tid;
    }
    sk[tid] = key;
  }
  __syncthreads();
  for (int ksz = 2; ksz <= SMax; ksz <<= 1){
    for (int jsz = ksz >> 1; jsz > 0; jsz >>= 1){
      for (int t = tid; t < SMax / 2; t += 512){
        int i = 2 * t - (t & (jsz - 1));
        int ixj = i ^ jsz;
        unsigned long long a = sk[i], c = sk[ixj];
        bool sw = ((i & ksz) == 0) ? (a < c) : (a > c);
        if (sw){ sk[i] = c; sk[ixj] = a; }
      }
      __syncthreads();
    }
  }
  if (tid < KKv){
    unsigned long long key = sk[tid];
    int p = (int)(key & 0xFFFFFu);
    float v = z0[p];
    xv[tid] = v;
    xc[tid] = Cols[b * SMax + p];
    XKval[b * KKv + tid] = v;
    XKcol[b * KKv + tid] = xc[tid];
  }
  __syncthreads();
  // residual r = y - sum_t xv[t]*At[xc[t]]  (2 rows per thread)
  int i1 = tid, i2 = tid + 512;
  float ra = Y[(size_t)b * Mdim + i1];
  float rb = Y[(size_t)b * Mdim + i2];
  for (int t = 0; t < KKv; ++t){
    const float* colp = At + (size_t)xc[t] * Mdim;
    float v = xv[t];
    ra = fmaf(-v, colp[i1], ra);
    rb = fmaf(-v, colp[i2], rb);
  }
  Rres[(size_t)b * Mdim + i1] = ra;
  Rres[(size_t)b * Mdim + i2] = rb;
  float ss = ra * ra + rb * rb;
  #pragma unroll
  for (int off = 32; off > 0; off >>= 1) ss += __shfl_xor(ss, off);
  if (lane == 0) red[w] = ss;
  __syncthreads();
  if (tid == 0){
    float tot = 0;
    for (int q = 0; q < 8; ++q) tot += red[q];
    if (tot < 1e-12f) Done[b] = 1;
  }
}

// ---------------------------------------------------------------- dense output
__global__ __launch_bounds__(1024) void k_output(const float* __restrict__ XKval, const int* __restrict__ XKcol,
        float* __restrict__ out){
  int b = blockIdx.x;
  __shared__ float xv[KKv];
  __shared__ int   xc[KKv];
  if (threadIdx.x < KKv){
    xv[threadIdx.x] = XKval[b * KKv + threadIdx.x];
    xc[threadIdx.x] = XKcol[b * KKv + threadIdx.x];
  }
  __syncthreads();
  int j = blockIdx.y * 1024 + threadIdx.x;
  float v = 0.0f;
  #pragma unroll
  for (int t = 0; t < KKv; ++t) v = (xc[t] == j) ? xv[t] : v;
  out[(size_t)b * Ndim + j] = v;
}

// ----------------------------------------------------------------
extern "C" void kernel_launch(void* const* d_in, const int* in_sizes, int n_in,
                              void* d_out, int out_size, void* d_ws, size_t ws_size,
                              hipStream_t stream){
  const float* Y = (const float*)d_in[0];   // [B][M]
  const float* A = (const float*)d_in[1];   // [M][N]
  float* ws = (float*)d_ws;
  size_t off = 0;
  float* At   = ws + off; off += (size_t)Ndim * Mdim;          // 4.19M
  float* G    = ws + off; off += (size_t)Bdim * SMax * SMax;   // 4.19M
  float* Gi   = ws + off; off += (size_t)Bdim * SMax * SMax;   // 4.19M
  float* V    = ws + off; off += (size_t)Bdim * SMax * K2v;    // 0.52M
  float* T    = ws + off; off += (size_t)Bdim * SMax * K2v;    // 0.52M
  float* Si   = ws + off; off += (size_t)Bdim * K2v * K2v;
  float* PP   = ws + off; off += (size_t)PQ * Bdim * Ndim;
  float* Rres = ws + off; off += (size_t)Bdim * Mdim;
  float* Bv   = ws + off; off += (size_t)Bdim * SMax;
  float* XKval = ws + off; off += (size_t)Bdim * KKv;
  int* XKcol = (int*)(ws + off); off += (size_t)Bdim * KKv;
  int* Cols  = (int*)(ws + off); off += (size_t)Bdim * SMax;
  int* Flags = (int*)(ws + off); off += (size_t)Bdim * Ndim;
  int* Sold  = (int*)(ws + off); off += Bdim;
  int* Snew  = (int*)(ws + off); off += Bdim;
  int* Done  = (int*)(ws + off); off += Bdim;

  k_init<<<256, 256, 0, stream>>>(Y, Rres, Flags, Sold, Snew, Done);
  k_transpose<<<dim3(Ndim / 32, Mdim / 32), dim3(32, 8), 0, stream>>>(A, At);
  for (int t = 0; t < NIT; ++t){
    k_proxy<<<dim3(Ndim / 256, PQ), 256, 0, stream>>>(A, Rres, PP);
    k_topk<<<Bdim, 1024, 0, stream>>>(PP, Flags, Cols, Sold, Snew, Done);
    k_gram<<<dim3(Bdim, 16), 256, 0, stream>>>(At, Y, G, Bv, Cols, Sold, Snew, Done);
    if (t > 0)
      k_V<<<dim3(Bdim, t), 256, 0, stream>>>(G, Gi, V, Sold, Snew, Done);
    k_schur<<<Bdim, 256, 0, stream>>>(G, V, Si, Sold, Snew, Done);
    if (t > 0)
      k_T<<<dim3(Bdim, t), 256, 0, stream>>>(V, Si, T, Sold, Snew, Done);
    k_upd<<<dim3(Bdim, t + 1, t + 1), 256, 0, stream>>>(Gi, T, V, Si, Sold, Snew, Done);
    k_solve<<<Bdim, 512, 0, stream>>>(G, Gi, Bv, At, Y, Cols, Snew, Done, XKval, XKcol, Rres);
  }
  k_output<<<dim3(Bdim, Ndim / 1024), 1024, 0, stream>>>(XKval, XKcol, (float*)d_out);
}